// Round 4
// baseline (318.851 us; speedup 1.0000x reference)
//
#include <hip/hip_runtime.h>
#include <hip/hip_bf16.h>

#define LL 4
#define NN 50000
#define DD 64
#define EE 500000
#define HID 256
#define KDIM 512
#define LN_EPS 1e-5f
#define NBK 1024          // src buckets: src>>6 -> 782 used, padded to 1024

typedef __bf16 bf16x8 __attribute__((ext_vector_type(8)));
typedef float f32x16 __attribute__((ext_vector_type(16)));

__device__ __forceinline__ void async16(const void* g, void* l) {
    __builtin_amdgcn_global_load_lds(
        (const __attribute__((address_space(1))) void*)g,
        (__attribute__((address_space(3))) void*)l, 16, 0, 0);
}

// VALU-only 16-lane sum reduce via DPP (no DS pipe).
template<int CTRL>
__device__ __forceinline__ float dpp_add(float x) {
    int p = __builtin_amdgcn_update_dpp(0, __builtin_bit_cast(int, x),
                                        CTRL, 0xF, 0xF, true);
    return x + __builtin_bit_cast(float, p);
}
__device__ __forceinline__ float red16(float x) {
    x = dpp_add<0xB1>(x);    // quad_perm(1,0,3,2)
    x = dpp_add<0x4E>(x);    // quad_perm(2,3,0,1)
    x = dpp_add<0x141>(x);   // row_half_mirror
    x = dpp_add<0x140>(x);   // row_mirror
    return x;
}

// ---------- kernel 1: t[l,n,d] = bf16( tanh( imp_l * h[l,n,d] ) ) ----------
__global__ void tanh_conv(const float* __restrict__ h, __bf16* __restrict__ t) {
    int i = (blockIdx.x * 256 + threadIdx.x) * 8;          // 12.8M elems, 8/thread
    int l = i / (NN * DD);
    float imp = (float)(l + 1) * 0.1f;
    const float4* p = (const float4*)(h + i);
    float4 a = p[0];
    float4 b = p[1];
    float x[8] = {a.x, a.y, a.z, a.w, b.x, b.y, b.z, b.w};
    bf16x8 r;
    #pragma unroll
    for (int j = 0; j < 8; ++j) {
        float e2 = __expf(2.0f * (imp * x[j]));
        r[j] = (__bf16)(1.0f - 2.0f / (e2 + 1.0f));
    }
    *(bf16x8*)(t + i) = r;
}

// ---------- kernel 2: W1 (256x512 f32) -> W'' (512 out-cols x 256 K) bf16 ----
__global__ void w2_conv(const float* __restrict__ w1, __bf16* __restrict__ o) {
    int t = blockIdx.x * 256 + threadIdx.x;                 // 16384 threads
    int j  = t & 511;
    int b  = t >> 9;              // [0,32)
    int k0 = (b >> 1) * 16 + (b & 1) * 8;
    int r  = j & 255;
    int col = (k0 >> 6) * 128 + ((j >> 8) ? 64 : 0) + (k0 & 63);
    const float4* p = (const float4*)(w1 + r * KDIM + col);
    float4 va = p[0];
    float4 vb = p[1];
    bf16x8 v;
    v[0] = (__bf16)va.x; v[1] = (__bf16)va.y; v[2] = (__bf16)va.z; v[3] = (__bf16)va.w;
    v[4] = (__bf16)vb.x; v[5] = (__bf16)vb.y; v[6] = (__bf16)vb.z; v[7] = (__bf16)vb.w;
    *(bf16x8*)(o + (size_t)t * 8) = v;
}

// ---------- kernel 3: node projections P[n][512] = [Ps | Pd+b1] (bf16) ------
__global__ __launch_bounds__(256, 2)
void node_proj(const __bf16* __restrict__ tb, const __bf16* __restrict__ w2c,
               const float* __restrict__ b1, __bf16* __restrict__ P) {
    __shared__ __align__(16) char smem[65536];
    __bf16* Bs = (__bf16*)smem;       // 32768 bf16 during GEMM
    float*  Cs = (float*)smem;        // 16384 f32 during store bounce

    const int tid  = threadIdx.x;
    const int wave = tid >> 6;
    const int lane = tid & 63;
    const int h32  = lane >> 5;
    const int c32  = lane & 31;
    const int cb   = blockIdx.y;      // which 128 of 512 out-cols
    const int n00  = blockIdx.x * 128;

    #pragma unroll
    for (int it = 0; it < 16; ++it) {
        int o = it * 2048 + tid * 8;   // elem offset within 32768-elem slice
        async16(w2c + (size_t)(o >> 10) * 4096 + cb * 1024 + (o & 1023), Bs + o);
    }

    float badd[8];
    {
        int c0 = (tid * 8) & 127;
        if (cb >= 2) {
            const float4* pb = (const float4*)(b1 + (cb - 2) * 128 + c0);
            float4 u = pb[0], v = pb[1];
            badd[0] = u.x; badd[1] = u.y; badd[2] = u.z; badd[3] = u.w;
            badd[4] = v.x; badd[5] = v.y; badd[6] = v.z; badd[7] = v.w;
        } else {
            #pragma unroll
            for (int z = 0; z < 8; ++z) badd[z] = 0.f;
        }
    }

    int node = n00 + wave * 32 + c32;
    if (node >= NN) node = NN - 1;
    uint4 a[16];
    #pragma unroll
    for (int u = 0; u < 16; ++u) {
        const __bf16* p = tb + (size_t)(u >> 2) * (NN * DD) + node * DD
                        + (u & 3) * 16 + h32 * 8;
        a[u] = *(const uint4*)p;
    }

    f32x16 acc[4];
    #pragma unroll
    for (int nt = 0; nt < 4; ++nt) acc[nt] = (f32x16)(0.f);

    __syncthreads();   // B resident

    #pragma unroll
    for (int u = 0; u < 16; ++u) {
        bf16x8 af = __builtin_bit_cast(bf16x8, a[u]);
        const __bf16* Bk = Bs + (u * 2 + h32) * 1024 + c32 * 8;
        #pragma unroll
        for (int nt = 0; nt < 4; ++nt) {
            bf16x8 bf = *(const bf16x8*)(Bk + nt * 256);
            acc[nt] = __builtin_amdgcn_mfma_f32_32x32x16_bf16(af, bf, acc[nt], 0, 0, 0);
        }
    }
    __syncthreads();

    // C/D 32x32 layout: col = c32, row = (r&3) + 8*(r>>2) + 4*h32
    #pragma unroll
    for (int nt = 0; nt < 4; ++nt) {
        #pragma unroll
        for (int r = 0; r < 16; ++r) {
            int nl = wave * 32 + (r & 3) + 8 * (r >> 2) + 4 * h32;
            Cs[nl * 128 + nt * 32 + c32] = acc[nt][r];
        }
    }
    __syncthreads();
    #pragma unroll
    for (int it = 0; it < 8; ++it) {
        int o  = it * 2048 + tid * 8;
        int nl = o >> 7;
        int n  = n00 + nl;
        if (n < NN) {
            bf16x8 v;
            #pragma unroll
            for (int z = 0; z < 8; ++z) v[z] = (__bf16)(Cs[o + z] + badd[z]);
            *(bf16x8*)(P + (size_t)n * 512 + cb * 128 + (o & 127)) = v;
        }
    }
}

// ---------- edge bucketing: counting sort by src>>6 (32 KB Ps window) -------
__global__ __launch_bounds__(1024) void eb_zero(int* __restrict__ cnt) {
    cnt[threadIdx.x] = 0;
}

__global__ __launch_bounds__(256) void eb_hist(const int* __restrict__ src,
                                               int* __restrict__ cnt) {
    __shared__ int h[NBK];
    for (int i = threadIdx.x; i < NBK; i += 256) h[i] = 0;
    __syncthreads();
    int base = blockIdx.x * 2048 + threadIdx.x * 8;
    #pragma unroll
    for (int z = 0; z < 8; ++z) {
        int e = base + z;
        if (e < EE) atomicAdd(&h[src[e] >> 6], 1);
    }
    __syncthreads();
    for (int i = threadIdx.x; i < NBK; i += 256)
        if (h[i]) atomicAdd(&cnt[i], h[i]);
}

__global__ __launch_bounds__(1024) void eb_scan(const int* __restrict__ cnt,
                                                int* __restrict__ offs) {
    __shared__ int s[NBK];
    int t = threadIdx.x;
    int my = cnt[t];
    s[t] = my;
    __syncthreads();
    for (int d = 1; d < NBK; d <<= 1) {
        int v = (t >= d) ? s[t - d] : 0;
        __syncthreads();
        s[t] += v;
        __syncthreads();
    }
    offs[t] = s[t] - my;          // exclusive prefix
}

__global__ __launch_bounds__(256) void eb_scatter(const int* __restrict__ src,
                                                  const int* __restrict__ dst,
                                                  int* __restrict__ offs,
                                                  int* __restrict__ srcp,
                                                  int* __restrict__ dstp,
                                                  int* __restrict__ eidp) {
    int base = blockIdx.x * 2048 + threadIdx.x * 8;
    #pragma unroll
    for (int z = 0; z < 8; ++z) {
        int e = base + z;
        if (e < EE) {
            int s = src[e];
            int pos = atomicAdd(&offs[s >> 6], 1);
            srcp[pos] = s;
            dstp[pos] = dst[e];
            eidp[pos] = e;
        }
    }
}

// ---------- kernel 4: per-edge gather + LN + ReLU + dot (bucketed) ----------
// Edges are pre-sorted by src bucket: consecutive edges share a 32 KB Ps
// window (avg degree 10 -> ~10x L1/L2 reuse on the src half). XCD-bijective
// swizzle keeps a bucket's workgroups on one XCD's L2. Output scattered to
// out[eid] (4 B/edge, L2-absorbed).
__global__ __launch_bounds__(256, 3)
void edge_out(const __bf16* __restrict__ P, const int* __restrict__ srcp,
              const int* __restrict__ dstp, const int* __restrict__ eidp,
              const float* __restrict__ w3, const float* __restrict__ b3,
              const float* __restrict__ gamma, const float* __restrict__ beta,
              float* __restrict__ out) {
    const int tid = threadIdx.x;
    const int g   = tid >> 4;
    const int j   = tid & 15;

    // XCD-bijective swizzle: nwg = 3907 = 8*488 + 3 (m204 formula)
    const int nwg = (EE + 127) / 128;
    const int q = nwg >> 3, r = nwg & 7;
    int xcd = blockIdx.x & 7, idx = blockIdx.x >> 3;
    int wg = (xcd < r ? xcd * (q + 1) : r * (q + 1) + (xcd - r) * q) + idx;

    float gv[16], btv[16], wv[16];
    {
        const float4* pg = (const float4*)(gamma + j * 16);
        const float4* pt = (const float4*)(beta + j * 16);
        const float4* pw = (const float4*)(w3 + j * 16);
        #pragma unroll
        for (int z = 0; z < 4; ++z) {
            float4 vg = pg[z], vt = pt[z], vw = pw[z];
            gv [z*4+0] = vg.x; gv [z*4+1] = vg.y; gv [z*4+2] = vg.z; gv [z*4+3] = vg.w;
            btv[z*4+0] = vt.x; btv[z*4+1] = vt.y; btv[z*4+2] = vt.z; btv[z*4+3] = vt.w;
            wv [z*4+0] = vw.x; wv [z*4+1] = vw.y; wv [z*4+2] = vw.z; wv [z*4+3] = vw.w;
        }
    }
    const float b3v = b3[0];
    const int e0 = wg * 128 + g * 8;

    // every lane loads the group's 8 src + 8 dst + 8 eid (L1 broadcast)
    int se[8], de[8], ee[8];
    if (e0 + 8 <= EE) {
        int4 sa = *(const int4*)(srcp + e0);
        int4 sb = *(const int4*)(srcp + e0 + 4);
        int4 da = *(const int4*)(dstp + e0);
        int4 db = *(const int4*)(dstp + e0 + 4);
        int4 ea = *(const int4*)(eidp + e0);
        int4 eb = *(const int4*)(eidp + e0 + 4);
        se[0]=sa.x; se[1]=sa.y; se[2]=sa.z; se[3]=sa.w;
        se[4]=sb.x; se[5]=sb.y; se[6]=sb.z; se[7]=sb.w;
        de[0]=da.x; de[1]=da.y; de[2]=da.z; de[3]=da.w;
        de[4]=db.x; de[5]=db.y; de[6]=db.z; de[7]=db.w;
        ee[0]=ea.x; ee[1]=ea.y; ee[2]=ea.z; ee[3]=ea.w;
        ee[4]=eb.x; ee[5]=eb.y; ee[6]=eb.z; ee[7]=eb.w;
    } else {                       // tail groups of the last block only
        #pragma unroll
        for (int z = 0; z < 8; ++z) {
            int ec = e0 + z; if (ec >= EE) ec = EE - 1;
            se[z] = srcp[ec]; de[z] = dstp[ec]; ee[z] = eidp[ec];
        }
    }

    uint4 s0[3], s1[3], d0[3], d1[3];   // 3-slot rotation, static indices

    #pragma unroll
    for (int i = 0; i < 2; ++i) {       // prologue: edges 0 and 1 in flight
        const uint4* ps = (const uint4*)(P + (size_t)se[i] * 512 + j * 16);
        const uint4* pd = (const uint4*)(P + (size_t)de[i] * 512 + 256 + j * 16);
        s0[i] = ps[0]; s1[i] = ps[1]; d0[i] = pd[0]; d1[i] = pd[1];
    }

    #pragma unroll
    for (int i = 0; i < 8; ++i) {
        if (i + 2 < 8) {                // prefetch edge i+2
            const int slot = (i + 2) % 3;
            const uint4* ps = (const uint4*)(P + (size_t)se[i+2] * 512 + j * 16);
            const uint4* pd = (const uint4*)(P + (size_t)de[i+2] * 512 + 256 + j * 16);
            s0[slot] = ps[0]; s1[slot] = ps[1]; d0[slot] = pd[0]; d1[slot] = pd[1];
        }
        const int cs = i % 3;
        bf16x8 a0 = __builtin_bit_cast(bf16x8, s0[cs]);
        bf16x8 a1 = __builtin_bit_cast(bf16x8, s1[cs]);
        bf16x8 c0 = __builtin_bit_cast(bf16x8, d0[cs]);
        bf16x8 c1 = __builtin_bit_cast(bf16x8, d1[cs]);
        float x[16];
        #pragma unroll
        for (int z = 0; z < 8; ++z) {
            x[z]     = (float)a0[z] + (float)c0[z];     // b1 already folded in P
            x[z + 8] = (float)a1[z] + (float)c1[z];
        }
        float sum = 0.f, sq = 0.f;
        #pragma unroll
        for (int z = 0; z < 16; ++z) {
            sum += x[z];
            sq   = fmaf(x[z], x[z], sq);
        }
        sum = red16(sum);               // VALU-only DPP reduce
        sq  = red16(sq);
        float mu = sum * (1.0f / 256.0f);
        float rs = rsqrtf(sq * (1.0f / 256.0f) - mu * mu + LN_EPS);
        float dot = 0.f;
        #pragma unroll
        for (int z = 0; z < 16; ++z) {
            float y = fmaxf((x[z] - mu) * rs * gv[z] + btv[z], 0.f);
            dot = fmaf(y, wv[z], dot);
        }
        dot = red16(dot);
        int e = e0 + i;
        if (j == 0 && e < EE) out[ee[i]] = dot + b3v;
    }
}

extern "C" void kernel_launch(void* const* d_in, const int* in_sizes, int n_in,
                              void* d_out, int out_size, void* d_ws, size_t ws_size,
                              hipStream_t stream) {
    const float* h_all  = (const float*)d_in[0];
    const int*   src    = (const int*)  d_in[1];
    const int*   dst    = (const int*)  d_in[2];
    const float* W1     = (const float*)d_in[3];
    const float* b1     = (const float*)d_in[4];
    const float* W3     = (const float*)d_in[5];
    const float* b3     = (const float*)d_in[6];
    const float* gamma2 = (const float*)d_in[7];
    const float* beta2  = (const float*)d_in[8];
    float* out = (float*)d_out;

    __bf16* tb  = (__bf16*)d_ws;                       // 12.8M bf16 = 25.6 MB
    __bf16* w2c = tb + (size_t)LL * NN * DD;           // 131072 bf16 = 256 KB
    __bf16* P   = w2c + 131072;                        // 50000*512 bf16 = 51.2 MB

    // bucket-sort scratch ALIASED into tb (dead after node_proj): 6 MB + 8 KB
    int* srcp = (int*)tb;
    int* dstp = srcp + EE;
    int* eidp = dstp + EE;
    int* cnt  = eidp + EE;
    int* offs = cnt + NBK;

    const int nsb = (EE + 2047) / 2048;                // 245 sort blocks

    tanh_conv<<<6250, 256, 0, stream>>>(h_all, tb);
    w2_conv<<<64, 256, 0, stream>>>(W1, w2c);
    node_proj<<<dim3((NN + 127) / 128, 4), 256, 0, stream>>>(tb, w2c, b1, P);
    eb_zero<<<1, NBK, 0, stream>>>(cnt);
    eb_hist<<<nsb, 256, 0, stream>>>(src, cnt);
    eb_scan<<<1, NBK, 0, stream>>>(cnt, offs);
    eb_scatter<<<nsb, 256, 0, stream>>>(src, dst, offs, srcp, dstp, eidp);
    edge_out<<<(EE + 127) / 128, 256, 0, stream>>>(P, srcp, dstp, eidp,
                                                   W3, b3, gamma2, beta2, out);
}

// Round 5
// 208.122 us; speedup vs baseline: 1.5320x; 1.5320x over previous
//
#include <hip/hip_runtime.h>
#include <hip/hip_bf16.h>

#define LL 4
#define NN 50000
#define DD 64
#define EE 500000
#define HID 256
#define KDIM 512
#define LN_EPS 1e-5f

typedef __bf16 bf16x8 __attribute__((ext_vector_type(8)));
typedef float f32x16 __attribute__((ext_vector_type(16)));
typedef unsigned int ui32x4 __attribute__((ext_vector_type(4)));

__device__ __forceinline__ void async16(const void* g, void* l) {
    __builtin_amdgcn_global_load_lds(
        (const __attribute__((address_space(1))) void*)g,
        (__attribute__((address_space(3))) void*)l, 16, 0, 0);
}

// volatile asm 16B load: stays exactly where written (no sinking), lets us
// put 32 loads in flight before the first waitcnt.
__device__ __forceinline__ ui32x4 load16_asm(const void* p) {
    ui32x4 v;
    asm volatile("global_load_dwordx4 %0, %1, off"
                 : "=&v"(v) : "v"(p) : "memory");
    return v;
}

// VALU-only 16-lane sum reduce via DPP (no DS pipe).
template<int CTRL>
__device__ __forceinline__ float dpp_add(float x) {
    int p = __builtin_amdgcn_update_dpp(0, __builtin_bit_cast(int, x),
                                        CTRL, 0xF, 0xF, true);
    return x + __builtin_bit_cast(float, p);
}
__device__ __forceinline__ float red16(float x) {
    x = dpp_add<0xB1>(x);    // quad_perm(1,0,3,2)
    x = dpp_add<0x4E>(x);    // quad_perm(2,3,0,1)
    x = dpp_add<0x141>(x);   // row_half_mirror
    x = dpp_add<0x140>(x);   // row_mirror
    return x;
}

// ---------- kernel 1: t[l,n,d] = bf16( tanh( imp_l * h[l,n,d] ) ) ----------
__global__ void tanh_conv(const float* __restrict__ h, __bf16* __restrict__ t) {
    int i = (blockIdx.x * 256 + threadIdx.x) * 8;          // 12.8M elems, 8/thread
    int l = i / (NN * DD);
    float imp = (float)(l + 1) * 0.1f;
    const float4* p = (const float4*)(h + i);
    float4 a = p[0];
    float4 b = p[1];
    float x[8] = {a.x, a.y, a.z, a.w, b.x, b.y, b.z, b.w};
    bf16x8 r;
    #pragma unroll
    for (int j = 0; j < 8; ++j) {
        float e2 = __expf(2.0f * (imp * x[j]));
        r[j] = (__bf16)(1.0f - 2.0f / (e2 + 1.0f));
    }
    *(bf16x8*)(t + i) = r;
}

// ---------- kernel 2: W1 (256x512 f32) -> W'' (512 out-cols x 256 K) bf16 ----
__global__ void w2_conv(const float* __restrict__ w1, __bf16* __restrict__ o) {
    int t = blockIdx.x * 256 + threadIdx.x;                 // 16384 threads
    int j  = t & 511;
    int b  = t >> 9;              // [0,32)
    int k0 = (b >> 1) * 16 + (b & 1) * 8;
    int r  = j & 255;
    int col = (k0 >> 6) * 128 + ((j >> 8) ? 64 : 0) + (k0 & 63);
    const float4* p = (const float4*)(w1 + r * KDIM + col);
    float4 va = p[0];
    float4 vb = p[1];
    bf16x8 v;
    v[0] = (__bf16)va.x; v[1] = (__bf16)va.y; v[2] = (__bf16)va.z; v[3] = (__bf16)va.w;
    v[4] = (__bf16)vb.x; v[5] = (__bf16)vb.y; v[6] = (__bf16)vb.z; v[7] = (__bf16)vb.w;
    *(bf16x8*)(o + (size_t)t * 8) = v;
}

// ---------- kernel 3: node projections P[n][512] = [Ps | Pd+b1] (bf16) ------
__global__ __launch_bounds__(256, 2)
void node_proj(const __bf16* __restrict__ tb, const __bf16* __restrict__ w2c,
               const float* __restrict__ b1, __bf16* __restrict__ P) {
    __shared__ __align__(16) char smem[65536];
    __bf16* Bs = (__bf16*)smem;       // 32768 bf16 during GEMM
    float*  Cs = (float*)smem;        // 16384 f32 during store bounce

    const int tid  = threadIdx.x;
    const int wave = tid >> 6;
    const int lane = tid & 63;
    const int h32  = lane >> 5;
    const int c32  = lane & 31;
    const int cb   = blockIdx.y;      // which 128 of 512 out-cols
    const int n00  = blockIdx.x * 128;

    #pragma unroll
    for (int it = 0; it < 16; ++it) {
        int o = it * 2048 + tid * 8;   // elem offset within 32768-elem slice
        async16(w2c + (size_t)(o >> 10) * 4096 + cb * 1024 + (o & 1023), Bs + o);
    }

    float badd[8];
    {
        int c0 = (tid * 8) & 127;
        if (cb >= 2) {
            const float4* pb = (const float4*)(b1 + (cb - 2) * 128 + c0);
            float4 u = pb[0], v = pb[1];
            badd[0] = u.x; badd[1] = u.y; badd[2] = u.z; badd[3] = u.w;
            badd[4] = v.x; badd[5] = v.y; badd[6] = v.z; badd[7] = v.w;
        } else {
            #pragma unroll
            for (int z = 0; z < 8; ++z) badd[z] = 0.f;
        }
    }

    int node = n00 + wave * 32 + c32;
    if (node >= NN) node = NN - 1;
    uint4 a[16];
    #pragma unroll
    for (int u = 0; u < 16; ++u) {
        const __bf16* p = tb + (size_t)(u >> 2) * (NN * DD) + node * DD
                        + (u & 3) * 16 + h32 * 8;
        a[u] = *(const uint4*)p;
    }

    f32x16 acc[4];
    #pragma unroll
    for (int nt = 0; nt < 4; ++nt) acc[nt] = (f32x16)(0.f);

    __syncthreads();   // B resident

    #pragma unroll
    for (int u = 0; u < 16; ++u) {
        bf16x8 af = __builtin_bit_cast(bf16x8, a[u]);
        const __bf16* Bk = Bs + (u * 2 + h32) * 1024 + c32 * 8;
        #pragma unroll
        for (int nt = 0; nt < 4; ++nt) {
            bf16x8 bf = *(const bf16x8*)(Bk + nt * 256);
            acc[nt] = __builtin_amdgcn_mfma_f32_32x32x16_bf16(af, bf, acc[nt], 0, 0, 0);
        }
    }
    __syncthreads();

    // C/D 32x32 layout: col = c32, row = (r&3) + 8*(r>>2) + 4*h32
    #pragma unroll
    for (int nt = 0; nt < 4; ++nt) {
        #pragma unroll
        for (int r = 0; r < 16; ++r) {
            int nl = wave * 32 + (r & 3) + 8 * (r >> 2) + 4 * h32;
            Cs[nl * 128 + nt * 32 + c32] = acc[nt][r];
        }
    }
    __syncthreads();
    #pragma unroll
    for (int it = 0; it < 8; ++it) {
        int o  = it * 2048 + tid * 8;
        int nl = o >> 7;
        int n  = n00 + nl;
        if (n < NN) {
            bf16x8 v;
            #pragma unroll
            for (int z = 0; z < 8; ++z) v[z] = (__bf16)(Cs[o + z] + badd[z]);
            *(bf16x8*)(P + (size_t)n * 512 + cb * 128 + (o & 127)) = v;
        }
    }
}

// ---------- kernel 4: per-edge gather + LN + ReLU + dot (deep-MLP) ----------
// WG = 256 thr = 16 groups of 16 lanes; group g handles 8 edges.
// Round-5 change (theory: latency/queue-bound, not service-rate-bound):
//   no pipe was saturated (HBM 55% achievable, L2 21%, VALU 53%) and
//   VGPR=64 proved the compiler sank all prefetches -> ~4 loads in flight.
//   Now ALL 32 gather loads (8 edges x 4 x dwordx4) are issued as volatile
//   inline asm (cannot sink), then ONE s_waitcnt vmcnt(0) + sched_barrier(0)
//   (rule #18), then all 8 edges' compute. 8x the memory-level parallelism.
//   launch_bounds(256,2) -> 256-VGPR budget for the 128 data regs.
__global__ __launch_bounds__(256, 2)
void edge_out(const __bf16* __restrict__ P, const int* __restrict__ src,
              const int* __restrict__ dst,
              const float* __restrict__ w3, const float* __restrict__ b3,
              const float* __restrict__ gamma, const float* __restrict__ beta,
              float* __restrict__ out) {
    const int tid = threadIdx.x;
    const int g   = tid >> 4;
    const int j   = tid & 15;

    // per-lane epilogue constants for h = j*16 .. +16 (kept resident)
    float gv[16], btv[16], wv[16];
    {
        const float4* pg = (const float4*)(gamma + j * 16);
        const float4* pt = (const float4*)(beta + j * 16);
        const float4* pw = (const float4*)(w3 + j * 16);
        #pragma unroll
        for (int z = 0; z < 4; ++z) {
            float4 vg = pg[z], vt = pt[z], vw = pw[z];
            gv [z*4+0] = vg.x; gv [z*4+1] = vg.y; gv [z*4+2] = vg.z; gv [z*4+3] = vg.w;
            btv[z*4+0] = vt.x; btv[z*4+1] = vt.y; btv[z*4+2] = vt.z; btv[z*4+3] = vt.w;
            wv [z*4+0] = vw.x; wv [z*4+1] = vw.y; wv [z*4+2] = vw.z; wv [z*4+3] = vw.w;
        }
    }
    #pragma unroll
    for (int z = 0; z < 16; ++z) {
        asm volatile("" : "+v"(gv[z]));
        asm volatile("" : "+v"(btv[z]));
        asm volatile("" : "+v"(wv[z]));
    }
    const float b3v = b3[0];
    const int e0 = blockIdx.x * 128 + g * 8;

    // every lane loads the group's 8 src + 8 dst indices (L1 broadcast)
    int se[8], de[8];
    if (e0 + 8 <= EE) {
        int4 sa = *(const int4*)(src + e0);
        int4 sb = *(const int4*)(src + e0 + 4);
        int4 da = *(const int4*)(dst + e0);
        int4 db = *(const int4*)(dst + e0 + 4);
        se[0]=sa.x; se[1]=sa.y; se[2]=sa.z; se[3]=sa.w;
        se[4]=sb.x; se[5]=sb.y; se[6]=sb.z; se[7]=sb.w;
        de[0]=da.x; de[1]=da.y; de[2]=da.z; de[3]=da.w;
        de[4]=db.x; de[5]=db.y; de[6]=db.z; de[7]=db.w;
    } else {
        #pragma unroll
        for (int z = 0; z < 8; ++z) {
            int ec = e0 + z; if (ec >= EE) ec = EE - 1;
            se[z] = src[ec]; de[z] = dst[ec];
        }
    }

    // issue ALL 32 gather loads (volatile asm: issue order pinned here)
    ui32x4 S0[8], S1[8], D0[8], D1[8];
    #pragma unroll
    for (int i = 0; i < 8; ++i) {
        const __bf16* ps = P + (size_t)se[i] * 512 + j * 16;
        const __bf16* pd = P + (size_t)de[i] * 512 + 256 + j * 16;
        S0[i] = load16_asm(ps);
        S1[i] = load16_asm(ps + 8);
        D0[i] = load16_asm(pd);
        D1[i] = load16_asm(pd + 8);
    }
    asm volatile("s_waitcnt vmcnt(0)" ::: "memory");
    __builtin_amdgcn_sched_barrier(0);   // nothing below may hoist above wait

    #pragma unroll
    for (int i = 0; i < 8; ++i) {
        bf16x8 a0 = __builtin_bit_cast(bf16x8, S0[i]);
        bf16x8 a1 = __builtin_bit_cast(bf16x8, S1[i]);
        bf16x8 c0 = __builtin_bit_cast(bf16x8, D0[i]);
        bf16x8 c1 = __builtin_bit_cast(bf16x8, D1[i]);
        float x[16];
        #pragma unroll
        for (int z = 0; z < 8; ++z) {
            x[z]     = (float)a0[z] + (float)c0[z];     // b1 already folded in P
            x[z + 8] = (float)a1[z] + (float)c1[z];
        }
        float sum = 0.f, sq = 0.f;
        #pragma unroll
        for (int z = 0; z < 16; ++z) {
            sum += x[z];
            sq   = fmaf(x[z], x[z], sq);
        }
        sum = red16(sum);               // VALU-only DPP reduce
        sq  = red16(sq);
        float mu = sum * (1.0f / 256.0f);
        float rs = rsqrtf(sq * (1.0f / 256.0f) - mu * mu + LN_EPS);
        float dot = 0.f;
        #pragma unroll
        for (int z = 0; z < 16; ++z) {
            float y = fmaxf((x[z] - mu) * rs * gv[z] + btv[z], 0.f);
            dot = fmaf(y, wv[z], dot);
        }
        dot = red16(dot);
        int e = e0 + i;
        if (j == 0 && e < EE) out[e] = dot + b3v;
    }
}

extern "C" void kernel_launch(void* const* d_in, const int* in_sizes, int n_in,
                              void* d_out, int out_size, void* d_ws, size_t ws_size,
                              hipStream_t stream) {
    const float* h_all  = (const float*)d_in[0];
    const int*   src    = (const int*)  d_in[1];
    const int*   dst    = (const int*)  d_in[2];
    const float* W1     = (const float*)d_in[3];
    const float* b1     = (const float*)d_in[4];
    const float* W3     = (const float*)d_in[5];
    const float* b3     = (const float*)d_in[6];
    const float* gamma2 = (const float*)d_in[7];
    const float* beta2  = (const float*)d_in[8];
    float* out = (float*)d_out;

    __bf16* tb  = (__bf16*)d_ws;                       // 12.8M bf16 = 25.6 MB
    __bf16* w2c = tb + (size_t)LL * NN * DD;           // 131072 bf16 = 256 KB
    __bf16* P   = w2c + 131072;                        // 50000*512 bf16 = 51.2 MB

    tanh_conv<<<6250, 256, 0, stream>>>(h_all, tb);
    w2_conv<<<64, 256, 0, stream>>>(W1, w2c);
    node_proj<<<dim3((NN + 127) / 128, 4), 256, 0, stream>>>(tb, w2c, b1, P);
    edge_out<<<(EE + 127) / 128, 256, 0, stream>>>(P, src, dst, W3, b3,
                                                   gamma2, beta2, out);
}

// Round 6
// 195.073 us; speedup vs baseline: 1.6345x; 1.0669x over previous
//
#include <hip/hip_runtime.h>
#include <hip/hip_bf16.h>

#define LL 4
#define NN 50000
#define DD 64
#define EE 500000
#define HID 256
#define KDIM 512
#define LN_EPS 1e-5f

typedef __bf16 bf16x8 __attribute__((ext_vector_type(8)));
typedef float f32x16 __attribute__((ext_vector_type(16)));

__device__ __forceinline__ void async16(const void* g, void* l) {
    __builtin_amdgcn_global_load_lds(
        (const __attribute__((address_space(1))) void*)g,
        (__attribute__((address_space(3))) void*)l, 16, 0, 0);
}

// VALU-only 16-lane sum reduce via DPP (no DS pipe).
template<int CTRL>
__device__ __forceinline__ float dpp_add(float x) {
    int p = __builtin_amdgcn_update_dpp(0, __builtin_bit_cast(int, x),
                                        CTRL, 0xF, 0xF, true);
    return x + __builtin_bit_cast(float, p);
}
__device__ __forceinline__ float red16(float x) {
    x = dpp_add<0xB1>(x);    // quad_perm(1,0,3,2)
    x = dpp_add<0x4E>(x);    // quad_perm(2,3,0,1)
    x = dpp_add<0x141>(x);   // row_half_mirror
    x = dpp_add<0x140>(x);   // row_mirror
    return x;
}

// ---------- kernel 1: W1 (256x512 f32) -> W'' (512 out-cols x 256 K) bf16 ----
// Out-col j<256: Ps row j (src cols of W1); j>=256: Pd row j-256 (dst cols).
// K index k means feature (l = k>>6, d = k&63) -> W1 col l*128 + 64*(j>=256) + d.
// Chunk layout: w2c[(b*512 + j)*8 + z], b = (k>>4)*2 + ((k>>3)&1), z = k&7.
__global__ void w2_conv(const float* __restrict__ w1, __bf16* __restrict__ o) {
    int t = blockIdx.x * 256 + threadIdx.x;                 // 16384 threads
    int j  = t & 511;
    int b  = t >> 9;              // [0,32)
    int k0 = (b >> 1) * 16 + (b & 1) * 8;
    int r  = j & 255;
    int col = (k0 >> 6) * 128 + ((j >> 8) ? 64 : 0) + (k0 & 63);
    const float4* p = (const float4*)(w1 + r * KDIM + col);
    float4 va = p[0];
    float4 vb = p[1];
    bf16x8 v;
    v[0] = (__bf16)va.x; v[1] = (__bf16)va.y; v[2] = (__bf16)va.z; v[3] = (__bf16)va.w;
    v[4] = (__bf16)vb.x; v[5] = (__bf16)vb.y; v[6] = (__bf16)vb.z; v[7] = (__bf16)vb.w;
    *(bf16x8*)(o + (size_t)t * 8) = v;
}

// ---------- kernel 2: FUSED tanh + node projections ------------------------
// P[n][512] = [Ps | Pd+b1] (bf16). Grid 391 x 1 (was 391 x 4).
// Round-6 restructuring:
//  - tanh_conv kernel ELIMINATED: A fragments are computed on the fly from
//    h (f32) -> tanh(imp_l * h) -> bf16. Kills the 25.6 MB tb intermediate
//    (77 MB of HBM round-trip) and one launch.
//  - cb (128-col block) is now an IN-KERNEL loop: A fragments loaded once
//    per node-tile instead of 4x (A traffic 102 MB -> 25.6 MB as f32 51.2).
//    B slice (64 KB) staged per cb into the same LDS; C bounced as bf16
//    through the (then-dead) first 32 KB of the B buffer.
__global__ __launch_bounds__(256, 2)
void node_proj(const float* __restrict__ h, const __bf16* __restrict__ w2c,
               const float* __restrict__ b1, __bf16* __restrict__ P) {
    __shared__ __align__(16) char smem[65536];
    __bf16* Bs  = (__bf16*)smem;      // 64 KB B slice during MFMA
    __bf16* Cs2 = (__bf16*)smem;      // 32 KB bf16 C bounce (phase-separated)

    const int tid  = threadIdx.x;
    const int wave = tid >> 6;
    const int lane = tid & 63;
    const int h32  = lane >> 5;
    const int c32  = lane & 31;
    const int n00  = blockIdx.x * 128;

    // stage B slice for cb=0: 16 x 2KB linear pieces
    #pragma unroll
    for (int it = 0; it < 16; ++it) {
        int o = it * 2048 + tid * 8;   // elem offset within 32768-elem slice
        async16(w2c + (size_t)(o >> 10) * 4096 + (o & 1023), Bs + o);
    }

    // A fragments: read h (f32) once, tanh+scale+convert in registers.
    // frag u: l = u>>2, k-chunk = (u&3)*16 + h32*8, m = c32 -> node.
    int node = n00 + wave * 32 + c32;
    if (node >= NN) node = NN - 1;
    bf16x8 af[16];
    #pragma unroll
    for (int u = 0; u < 16; ++u) {
        int l = u >> 2;
        float imp = (float)(l + 1) * 0.1f;
        const float* p = h + (size_t)l * (NN * DD) + node * DD
                       + (u & 3) * 16 + h32 * 8;
        float4 va = *(const float4*)p;
        float4 vb = *(const float4*)(p + 4);
        float xv[8] = {va.x, va.y, va.z, va.w, vb.x, vb.y, vb.z, vb.w};
        #pragma unroll
        for (int z = 0; z < 8; ++z) {
            float e2 = __expf(2.0f * (imp * xv[z]));
            af[u][z] = (__bf16)(1.0f - 2.0f / (e2 + 1.0f));
        }
    }

    for (int cb = 0; cb < 4; ++cb) {
        __syncthreads();               // B(cb) resident; LDS free of prior phase

        f32x16 acc[4];
        #pragma unroll
        for (int nt = 0; nt < 4; ++nt) acc[nt] = (f32x16)(0.f);

        #pragma unroll
        for (int u = 0; u < 16; ++u) {
            const __bf16* Bk = Bs + (u * 2 + h32) * 1024 + c32 * 8;
            #pragma unroll
            for (int nt = 0; nt < 4; ++nt) {
                bf16x8 bf = *(const bf16x8*)(Bk + nt * 256);
                acc[nt] = __builtin_amdgcn_mfma_f32_32x32x16_bf16(af[u], bf, acc[nt], 0, 0, 0);
            }
        }
        __syncthreads();               // all waves done reading Bs

        // b1 fold for dst half (cols 256..511): col = cb*128 + nt*32 + c32
        float b1v[4];
        #pragma unroll
        for (int nt = 0; nt < 4; ++nt)
            b1v[nt] = (cb >= 2) ? b1[(cb - 2) * 128 + nt * 32 + c32] : 0.f;

        // bounce C (bf16) through LDS for coalesced row stores
        // C/D 32x32 layout: col = c32, row = (r&3) + 8*(r>>2) + 4*h32
        #pragma unroll
        for (int nt = 0; nt < 4; ++nt) {
            #pragma unroll
            for (int r = 0; r < 16; ++r) {
                int nl = wave * 32 + (r & 3) + 8 * (r >> 2) + 4 * h32;
                Cs2[nl * 128 + nt * 32 + c32] = (__bf16)(acc[nt][r] + b1v[nt]);
            }
        }
        __syncthreads();               // Cs2 complete

        #pragma unroll
        for (int it = 0; it < 8; ++it) {
            int o  = it * 2048 + tid * 8;
            int nl = o >> 7;
            int n  = n00 + nl;
            if (n < NN)
                *(bf16x8*)(P + (size_t)n * 512 + cb * 128 + (o & 127)) =
                    *(const bf16x8*)(Cs2 + o);
        }

        if (cb < 3) {
            __syncthreads();           // store-side LDS reads done before overwrite
            #pragma unroll
            for (int it = 0; it < 16; ++it) {
                int o = it * 2048 + tid * 8;
                async16(w2c + (size_t)(o >> 10) * 4096 + (cb + 1) * 1024 + (o & 1023),
                        Bs + o);
            }
        }
    }
}

// ---------- kernel 3: per-edge gather + LN + ReLU + dot ---------------------
// Reverted to the best-measured variant (72 us): DPP reduces, direct index
// loads, 3-slot rotation, launch_bounds(256,3). R5's forced-MLP volatile-asm
// variant regressed (84.6 us: compiler spilled the 128 in-flight dest regs,
// occupancy 36%->18%). Across R2-R5 this stage is invariant ~70-72 us under
// every compute/latency restructuring -> cache-hierarchy service bound on the
// 500 MB random gather.
__global__ __launch_bounds__(256, 3)
void edge_out(const __bf16* __restrict__ P, const int* __restrict__ src,
              const int* __restrict__ dst,
              const float* __restrict__ w3, const float* __restrict__ b3,
              const float* __restrict__ gamma, const float* __restrict__ beta,
              float* __restrict__ out) {
    const int tid = threadIdx.x;
    const int g   = tid >> 4;
    const int j   = tid & 15;

    float gv[16], btv[16], wv[16];
    {
        const float4* pg = (const float4*)(gamma + j * 16);
        const float4* pt = (const float4*)(beta + j * 16);
        const float4* pw = (const float4*)(w3 + j * 16);
        #pragma unroll
        for (int z = 0; z < 4; ++z) {
            float4 vg = pg[z], vt = pt[z], vw = pw[z];
            gv [z*4+0] = vg.x; gv [z*4+1] = vg.y; gv [z*4+2] = vg.z; gv [z*4+3] = vg.w;
            btv[z*4+0] = vt.x; btv[z*4+1] = vt.y; btv[z*4+2] = vt.z; btv[z*4+3] = vt.w;
            wv [z*4+0] = vw.x; wv [z*4+1] = vw.y; wv [z*4+2] = vw.z; wv [z*4+3] = vw.w;
        }
    }
    #pragma unroll
    for (int z = 0; z < 16; ++z) {
        asm volatile("" : "+v"(gv[z]));
        asm volatile("" : "+v"(btv[z]));
        asm volatile("" : "+v"(wv[z]));
    }
    const float b3v = b3[0];
    const int e0 = blockIdx.x * 128 + g * 8;

    // every lane loads the group's 8 src + 8 dst indices (L1 broadcast)
    int se[8], de[8];
    if (e0 + 8 <= EE) {
        int4 sa = *(const int4*)(src + e0);
        int4 sb = *(const int4*)(src + e0 + 4);
        int4 da = *(const int4*)(dst + e0);
        int4 db = *(const int4*)(dst + e0 + 4);
        se[0]=sa.x; se[1]=sa.y; se[2]=sa.z; se[3]=sa.w;
        se[4]=sb.x; se[5]=sb.y; se[6]=sb.z; se[7]=sb.w;
        de[0]=da.x; de[1]=da.y; de[2]=da.z; de[3]=da.w;
        de[4]=db.x; de[5]=db.y; de[6]=db.z; de[7]=db.w;
    } else {
        #pragma unroll
        for (int z = 0; z < 8; ++z) {
            int ec = e0 + z; if (ec >= EE) ec = EE - 1;
            se[z] = src[ec]; de[z] = dst[ec];
        }
    }

    uint4 s0[3], s1[3], d0[3], d1[3];   // 3-slot rotation, static indices

    #pragma unroll
    for (int i = 0; i < 2; ++i) {       // prologue: edges 0 and 1 in flight
        const uint4* ps = (const uint4*)(P + (size_t)se[i] * 512 + j * 16);
        const uint4* pd = (const uint4*)(P + (size_t)de[i] * 512 + 256 + j * 16);
        s0[i] = ps[0]; s1[i] = ps[1]; d0[i] = pd[0]; d1[i] = pd[1];
    }

    #pragma unroll
    for (int i = 0; i < 8; ++i) {
        if (i + 2 < 8) {                // prefetch edge i+2
            const int slot = (i + 2) % 3;
            const uint4* ps = (const uint4*)(P + (size_t)se[i+2] * 512 + j * 16);
            const uint4* pd = (const uint4*)(P + (size_t)de[i+2] * 512 + 256 + j * 16);
            s0[slot] = ps[0]; s1[slot] = ps[1]; d0[slot] = pd[0]; d1[slot] = pd[1];
        }
        const int cs = i % 3;
        bf16x8 a0 = __builtin_bit_cast(bf16x8, s0[cs]);
        bf16x8 a1 = __builtin_bit_cast(bf16x8, s1[cs]);
        bf16x8 c0 = __builtin_bit_cast(bf16x8, d0[cs]);
        bf16x8 c1 = __builtin_bit_cast(bf16x8, d1[cs]);
        float x[16];
        #pragma unroll
        for (int z = 0; z < 8; ++z) {
            x[z]     = (float)a0[z] + (float)c0[z];     // b1 already folded in P
            x[z + 8] = (float)a1[z] + (float)c1[z];
        }
        float sum = 0.f, sq = 0.f;
        #pragma unroll
        for (int z = 0; z < 16; ++z) {
            sum += x[z];
            sq   = fmaf(x[z], x[z], sq);
        }
        sum = red16(sum);               // VALU-only DPP reduce
        sq  = red16(sq);
        float mu = sum * (1.0f / 256.0f);
        float rs = rsqrtf(sq * (1.0f / 256.0f) - mu * mu + LN_EPS);
        float dot = 0.f;
        #pragma unroll
        for (int z = 0; z < 16; ++z) {
            float y = fmaxf((x[z] - mu) * rs * gv[z] + btv[z], 0.f);
            dot = fmaf(y, wv[z], dot);
        }
        dot = red16(dot);
        int e = e0 + i;
        if (j == 0 && e < EE) out[e] = dot + b3v;
    }
}

extern "C" void kernel_launch(void* const* d_in, const int* in_sizes, int n_in,
                              void* d_out, int out_size, void* d_ws, size_t ws_size,
                              hipStream_t stream) {
    const float* h_all  = (const float*)d_in[0];
    const int*   src    = (const int*)  d_in[1];
    const int*   dst    = (const int*)  d_in[2];
    const float* W1     = (const float*)d_in[3];
    const float* b1     = (const float*)d_in[4];
    const float* W3     = (const float*)d_in[5];
    const float* b3     = (const float*)d_in[6];
    const float* gamma2 = (const float*)d_in[7];
    const float* beta2  = (const float*)d_in[8];
    float* out = (float*)d_out;

    __bf16* w2c = (__bf16*)d_ws;                       // 131072 bf16 = 256 KB
    __bf16* P   = w2c + 131072;                        // 50000*512 bf16 = 51.2 MB

    w2_conv<<<64, 256, 0, stream>>>(W1, w2c);
    node_proj<<<(NN + 127) / 128, 256, 0, stream>>>(h_all, w2c, b1, P);
    edge_out<<<(EE + 127) / 128, 256, 0, stream>>>(P, src, dst, W3, b3,
                                                   gamma2, beta2, out);
}